// Round 9
// baseline (303.897 us; speedup 1.0000x reference)
//
#include <hip/hip_runtime.h>
#include <cmath>

#define HIDC 48

// ---------------------------------------------------------------------------
// block-wide mean/var over NPIX values spread across 16 waves (1024 threads).
// ---------------------------------------------------------------------------
__device__ __forceinline__ void block_meanvar1024(float s, float s2, float* red,
                                                  float cntinv, float& m, float& v)
{
#pragma unroll
    for (int off = 32; off > 0; off >>= 1) {
        s  += __shfl_down(s, off);
        s2 += __shfl_down(s2, off);
    }
    int wid  = threadIdx.x >> 6;   // 0..15
    int lane = threadIdx.x & 63;
    if (lane == 0) { red[wid] = s; red[16 + wid] = s2; }
    __syncthreads();
    if (threadIdx.x == 0) {
        float ts = 0.f, ts2 = 0.f;
#pragma unroll
        for (int i = 0; i < 16; ++i) { ts += red[i]; ts2 += red[16 + i]; }
        red[32] = ts; red[33] = ts2;
    }
    __syncthreads();
    float mean = red[32] * cntinv;
    m = mean;
    v = red[33] * cntinv - mean * mean;
    __syncthreads();
}

// ---------------------------------------------------------------------------
// Split-K partial conv3x3(SAME, zero-pad), NO bias (bias cancels in the
// following instance-norm; SK-conv bias is added in apply_fused).
// Each block: COG couts x ROWS rows x W cols over NCH=24 input channels;
// partial written to out + half*4*COUT*NPIX; the next norm sums partials.
//
// r9: XCD-aware grid order. Grid is (z, rt, cg) with z=(n,half) FASTEST:
// flattened bid % 8 == z, and MI355X assigns blocks to its 8 XCDs
// round-robin by bid — so each XCD owns exactly ONE (n,half) input slice
// (1.57MB, L2-resident). r7 counters showed the old (cg,rt,z) order fetched
// the input from HBM once PER XCD (FETCH 24.6MB = 8x input). L2-hit staging
// (~200cyc) vs HBM (~900cyc) attacks the latency behind VALUBusy=16%.
//  - SCALAR staging (r7 lesson: float4 staging tuples demoted to scratch
//    -> 143MB write-back, 57us. Keep scalars.)
//  - Stage addresses precomputed ONCE into off[] (-1 = zero pad).
//  - PW = W+4: conflict-free float2/scalar LDS windows.
//  - Double-buffered LDS, ONE barrier per stage.
//  - r3 lesson: never stage strided-by-4 global reads.
//  - r5 lesson: no grid-wide syncs (54us each).
// ---------------------------------------------------------------------------
template <int H, int W, int ROWS, int COG, int CPS, int PXT, int NCH, int COUT>
__global__ __launch_bounds__(ROWS*(W/PXT)) void conv_tile(
    const float* __restrict__ in,    // (N, 48, H, W)
    const float* __restrict__ wgt,   // (COUT, 48, 3, 3)
    float* __restrict__ out)         // (2, N, COUT, H, W) partials
{
    constexpr int THREADS = ROWS * (W / PXT);
    constexpr int NPIX = H * W;
    constexpr int PW   = W + 4;
    constexpr int CHSZ = (ROWS + 2) * PW;
    constexpr int LSZ  = CPS * CHSZ;
    constexpr int TXN  = W / PXT;          // threads per row
    constexpr int NS   = NCH / CPS;
    constexpr int LPT  = (LSZ + THREADS - 1) / THREADS;

    __shared__ float plane[2][LSZ];

    const int t    = threadIdx.x;
    const int z    = blockIdx.x;           // (n,half) — fastest => one per XCD
    const int rt   = blockIdx.y;
    const int cg   = blockIdx.z;
    const int half = z & 1;
    const int n    = z >> 1;
    const int co0  = cg * COG;
    const int cin0 = half * NCH;
    const int tx   = t % TXN;
    const int ty   = t / TXN;              // row within tile
    const int x0   = tx * PXT;
    const int r0   = rt * ROWS;
    const size_t OSTRIDE = (size_t)4 * COUT * NPIX;

    float acc[COG][PXT];
#pragma unroll
    for (int co = 0; co < COG; ++co)
#pragma unroll
        for (int p = 0; p < PXT; ++p) acc[co][p] = 0.f;

    const float* inb = in + ((size_t)n * 48 + cin0) * NPIX;

    // precompute staging offsets (loop-invariant across stages)
    int off[LPT];
#pragma unroll
    for (int k = 0; k < LPT; ++k) {
        int i = t + k * THREADS;
        off[k] = -1;
        if (i < LSZ) {
            int ch  = i / CHSZ;
            int rem = i % CHSZ;
            int ly  = rem / PW, lx = rem % PW;
            int gy  = r0 + ly - 1, gx = lx - 1;
            if (gy >= 0 && gy < H && gx >= 0 && gx < W)
                off[k] = ch * NPIX + gy * W + gx;
        }
    }

    // prefetch stage 0
    float pref[LPT];
#pragma unroll
    for (int k = 0; k < LPT; ++k)
        pref[k] = (off[k] >= 0) ? inb[off[k]] : 0.f;

    int buf = 0;
    for (int s = 0; s < NS; ++s) {
        float cur[LPT];
#pragma unroll
        for (int k = 0; k < LPT; ++k) cur[k] = pref[k];
        if (s + 1 < NS) {
            const float* nb = inb + (size_t)(s + 1) * CPS * NPIX;
#pragma unroll
            for (int k = 0; k < LPT; ++k)
                pref[k] = (off[k] >= 0) ? nb[off[k]] : 0.f;
        }
#pragma unroll
        for (int k = 0; k < LPT; ++k) {
            int i = t + k * THREADS;
            if (i < LSZ) plane[buf][i] = cur[k];
        }
        __syncthreads();

#pragma unroll
        for (int c = 0; c < CPS; ++c) {
            const float* P = &plane[buf][c * CHSZ];
            float wv[COG][9];
#pragma unroll
            for (int co = 0; co < COG; ++co)
#pragma unroll
                for (int k = 0; k < 9; ++k)
                    wv[co][k] = wgt[((size_t)(co0 + co) * 48 + cin0 + s * CPS + c) * 9 + k];
            // window rows ty..ty+2, cols x0..x0+PXT+1
            float vr[3][PXT + 2];
            if constexpr (PXT == 2) {
#pragma unroll
                for (int r = 0; r < 3; ++r) {
                    float2 a = *(const float2*)(P + (ty + r) * PW + x0);
                    float2 b = *(const float2*)(P + (ty + r) * PW + x0 + 2);
                    vr[r][0] = a.x; vr[r][1] = a.y; vr[r][2] = b.x; vr[r][3] = b.y;
                }
            } else {
#pragma unroll
                for (int r = 0; r < 3; ++r)
#pragma unroll
                    for (int j = 0; j < PXT + 2; ++j)
                        vr[r][j] = P[(ty + r) * PW + x0 + j];
            }
#pragma unroll
            for (int co = 0; co < COG; ++co)
#pragma unroll
                for (int p = 0; p < PXT; ++p) {
                    float s0 = vr[0][p]     * wv[co][0] + vr[0][p + 1] * wv[co][1]
                             + vr[0][p + 2] * wv[co][2] + vr[1][p]     * wv[co][3]
                             + vr[1][p + 1] * wv[co][4] + vr[1][p + 2] * wv[co][5]
                             + vr[2][p]     * wv[co][6] + vr[2][p + 1] * wv[co][7]
                             + vr[2][p + 2] * wv[co][8];
                    acc[co][p] += s0;
                }
        }
        buf ^= 1;
    }

#pragma unroll
    for (int co = 0; co < COG; ++co) {
        float* op = out + half * OSTRIDE
                  + (((size_t)n * COUT + co0 + co) * H + r0 + ty) * W + x0;
        if (PXT == 2) {
            *(float2*)op = make_float2(acc[co][0], acc[co][1]);
        } else {
#pragma unroll
            for (int p = 0; p < PXT; ++p) op[p] = acc[co][p];
        }
    }
}

// ---------------------------------------------------------------------------
// Per-plane epilogue on the SUM of two split-K partials:
//   MODE 0: inorm, prelu, inorm, +res    MODE 1: inorm, prelu
//   POOL 1: (MODE 0 only, NPIX=4096) thread owns a 2x2 quad; after the
//           residual add, pools max-2x2 in-register and writes the 32x32
//           plane (fuses maxpool2, saves a dispatch + round-trip).
// Non-POOL TY=4 path vectorized (r8): thread owns t*4..t*4+3.
// ---------------------------------------------------------------------------
template <int NPIX, int MODE, int POOL>
__global__ __launch_bounds__(1024) void norm_block(
    const float* __restrict__ c0,
    const float* __restrict__ c1,
    const float* __restrict__ res,
    const float* __restrict__ aptr,
    float* __restrict__ out)
{
    constexpr int TY = NPIX / 1024;
    constexpr bool VEC = (TY == 4) && (POOL == 0);
    __shared__ float red[34];
    const int t  = threadIdx.x;
    const int co = blockIdx.x;
    const int n  = blockIdx.y;
    const size_t base = ((size_t)n * 48 + co) * NPIX;
    constexpr float cntinv = 1.f / (float)NPIX;

    float acc[TY];
    size_t q = 0;
    if constexpr (POOL) {
        const int i = t >> 5, j = t & 31;       // quad (2i,2j)
        q = base + (size_t)i * 128 + j * 2;
        float2 a0 = *(const float2*)(c0 + q);
        float2 a1 = *(const float2*)(c0 + q + 64);
        float2 b0 = *(const float2*)(c1 + q);
        float2 b1 = *(const float2*)(c1 + q + 64);
        acc[0] = a0.x + b0.x; acc[1] = a0.y + b0.y;
        acc[2] = a1.x + b1.x; acc[3] = a1.y + b1.y;
    } else if constexpr (VEC) {
        q = base + (size_t)t * 4;
        float4 a4 = *(const float4*)(c0 + q);
        float4 b4 = *(const float4*)(c1 + q);
        acc[0] = a4.x + b4.x; acc[1] = a4.y + b4.y;
        acc[2] = a4.z + b4.z; acc[3] = a4.w + b4.w;
    } else {
#pragma unroll
        for (int r = 0; r < TY; ++r)
            acc[r] = c0[base + t + r * 1024] + c1[base + t + r * 1024];
    }

    {
        float s = 0.f, s2 = 0.f;
#pragma unroll
        for (int r = 0; r < TY; ++r) { s += acc[r]; s2 += acc[r] * acc[r]; }
        float m, v;
        block_meanvar1024(s, s2, red, cntinv, m, v);
        float rr = rsqrtf(v + 1e-5f);
#pragma unroll
        for (int r = 0; r < TY; ++r) acc[r] = (acc[r] - m) * rr;
    }

    const float a = aptr[0];
#pragma unroll
    for (int r = 0; r < TY; ++r) acc[r] = acc[r] >= 0.f ? acc[r] : a * acc[r];

    if (MODE == 0) {
        float s = 0.f, s2 = 0.f;
#pragma unroll
        for (int r = 0; r < TY; ++r) { s += acc[r]; s2 += acc[r] * acc[r]; }
        float m, v;
        block_meanvar1024(s, s2, red, cntinv, m, v);
        float rr = rsqrtf(v + 1e-5f);
        if constexpr (POOL) {
            float2 r0v = *(const float2*)(res + q);
            float2 r1v = *(const float2*)(res + q + 64);
            acc[0] = (acc[0] - m) * rr + r0v.x;
            acc[1] = (acc[1] - m) * rr + r0v.y;
            acc[2] = (acc[2] - m) * rr + r1v.x;
            acc[3] = (acc[3] - m) * rr + r1v.y;
        } else if constexpr (VEC) {
            float4 r4 = *(const float4*)(res + q);
            acc[0] = (acc[0] - m) * rr + r4.x;
            acc[1] = (acc[1] - m) * rr + r4.y;
            acc[2] = (acc[2] - m) * rr + r4.z;
            acc[3] = (acc[3] - m) * rr + r4.w;
        } else {
#pragma unroll
            for (int r = 0; r < TY; ++r)
                acc[r] = (acc[r] - m) * rr + res[base + t + r * 1024];
        }
    }

    if constexpr (POOL) {
        out[(((size_t)n * 48 + co) << 10) + t] =
            fmaxf(fmaxf(acc[0], acc[1]), fmaxf(acc[2], acc[3]));
    } else if constexpr (VEC) {
        *(float4*)(out + q) = make_float4(acc[0], acc[1], acc[2], acc[3]);
    } else {
#pragma unroll
        for (int r = 0; r < TY; ++r) out[base + t + r * 1024] = acc[r];
    }
}

// ---------------------------------------------------------------------------
__global__ __launch_bounds__(256) void downsample4(const float* __restrict__ xin,
                                                   float* __restrict__ o)
{
    int idx = blockIdx.x * 256 + threadIdx.x;        // 786432
    int j = idx & 63;
    int i = (idx >> 6) & 63;
    int nc = idx >> 12;
    o[idx] = xin[((size_t)nc * 256 + i * 4) * 256 + j * 4];
}

// ---------------------------------------------------------------------------
// Fused: bilinear 8x upsample of skernel partials (sk0+sk1+bias), per-pixel
// softmax, 3x3 reflect-padded apply to x.
// r9: FOUR output rows per block — grid (16, 64). A 1-row block re-read its
// h±1 neighbor rows (x read 3x = 150MB through cache); 6 staged rows for
// 4 outputs cuts that to 1.5x and halves issued loads. All 18 x-row loads
// hoisted to the top (independent of softmax). kvs[4][9][256] in LDS
// (40KB/block -> 3 blocks/CU, fine for a memory-bound kernel).
// Halo via cross-lane shuffle; per-k reflection handles h=-1/256 edges.
// ---------------------------------------------------------------------------
__global__ __launch_bounds__(256) void apply_fused(const float* __restrict__ x,
                                                   const float* __restrict__ sk0,
                                                   const float* __restrict__ sk1,
                                                   const float* __restrict__ kb2,
                                                   float* __restrict__ out)
{
    __shared__ float skr[9][3][32];
    __shared__ float kvs[4][9][256];
    const int bx = blockIdx.x;
    const int n  = bx >> 2;
    const int cg = bx & 3;
    const int h0 = blockIdx.y * 4;
    const int t  = threadIdx.x;

    const int wq = t & 63;           // lane within wave == pixel quad
    const int cl = t >> 6;           // wave id == channel subgroup
    const int w4 = wq * 4;
    const int c0ch = cg * 12 + cl * 3;
    const float* xb = x + ((size_t)n * HIDC + c0ch) * 65536;
    float* ob = out + ((size_t)n * HIDC + c0ch) * 65536;

    // hoist all 18 x-row loads (rows h0-1 .. h0+4, reflect-mapped)
    float4 F[3][6];
#pragma unroll
    for (int c = 0; c < 3; ++c) {
        const float* xp = xb + (size_t)c * 65536;
#pragma unroll
        for (int k = 0; k < 6; ++k) {
            int g = h0 - 1 + k;
            g = (g < 0) ? 1 : (g > 255 ? 254 : g);
            F[c][k] = *(const float4*)(xp + g * 256 + w4);
        }
    }

    // stage the 3 skernel source rows this block can touch: r_0 .. r_0+2
    const int r_0 = (h0 * 31) / 255;
    for (int i = t; i < 864; i += 256) {
        int p = i / 96, rem = i % 96;
        int rsel = rem >> 5, c = rem & 31;
        int rr = min(r_0 + rsel, 31);
        int idx = ((n * 9 + p) * 32 + rr) * 32 + c;
        skr[p][rsel][c] = sk0[idx] + sk1[idx] + kb2[p];
    }
    __syncthreads();

    // per-pixel bilinear + softmax for 4 rows (thread t = column t)
    {
        float fcs = (float)t * 31.0f / 255.0f;
        int c0 = (int)fcs;
        float fx = fcs - (float)c0;
        int c1 = min(c0 + 1, 31);
#pragma unroll
        for (int ro = 0; ro < 4; ++ro) {
            float fs = (float)(h0 + ro) * 31.0f / 255.0f;
            int rh = (int)fs;
            float fh = fs - (float)rh;
            int a_ = rh - r_0;           // 0 or 1
            int b_ = a_ + 1;             // 1 or 2
            float kv[9];
            float mx = -1e30f;
#pragma unroll
            for (int p = 0; p < 9; ++p) {
                float v0 = skr[p][a_][c0] * (1.f - fx) + skr[p][a_][c1] * fx;
                float v1 = skr[p][b_][c0] * (1.f - fx) + skr[p][b_][c1] * fx;
                float v  = v0 * (1.f - fh) + v1 * fh;
                kv[p] = v;
                mx = fmaxf(mx, v);
            }
            float ss = 0.f;
#pragma unroll
            for (int p = 0; p < 9; ++p) { kv[p] = __expf(kv[p] - mx); ss += kv[p]; }
            float inv = 1.f / ss;
#pragma unroll
            for (int p = 0; p < 9; ++p) kvs[ro][p][t] = kv[p] * inv;
        }
    }
    __syncthreads();

#pragma unroll
    for (int ro = 0; ro < 4; ++ro) {
        float kv[4][9];
#pragma unroll
        for (int p = 0; p < 9; ++p) {
            float4 v = *(const float4*)&kvs[ro][p][w4];
            kv[0][p] = v.x; kv[1][p] = v.y; kv[2][p] = v.z; kv[3][p] = v.w;
        }
#pragma unroll
        for (int c = 0; c < 3; ++c) {
            float4 fm = F[c][ro];
            float4 fc = F[c][ro + 1];
            float4 fp = F[c][ro + 2];
            float lm = __shfl_up(fm.w, 1);   if (wq == 0)  lm = fm.y;
            float lc = __shfl_up(fc.w, 1);   if (wq == 0)  lc = fc.y;
            float lp = __shfl_up(fp.w, 1);   if (wq == 0)  lp = fp.y;
            float rmr = __shfl_down(fm.x, 1); if (wq == 63) rmr = fm.z;
            float rcr = __shfl_down(fc.x, 1); if (wq == 63) rcr = fc.z;
            float rpr = __shfl_down(fp.x, 1); if (wq == 63) rpr = fp.z;
            float vm[6] = { lm, fm.x, fm.y, fm.z, fm.w, rmr };
            float vc[6] = { lc, fc.x, fc.y, fc.z, fc.w, rcr };
            float vp[6] = { lp, fp.x, fp.y, fp.z, fp.w, rpr };
            float4 o;
            float* op = &o.x;
#pragma unroll
            for (int j = 0; j < 4; ++j) {
                op[j] = kv[j][0] * vm[j] + kv[j][1] * vm[j + 1] + kv[j][2] * vm[j + 2]
                      + kv[j][3] * vc[j] + kv[j][4] * vc[j + 1] + kv[j][5] * vc[j + 2]
                      + kv[j][6] * vp[j] + kv[j][7] * vp[j + 1] + kv[j][8] * vp[j + 2];
            }
            *(float4*)(ob + (size_t)c * 65536 + (h0 + ro) * 256 + w4) = o;
        }
    }
}

extern "C" void kernel_launch(void* const* d_in, const int* in_sizes, int n_in,
                              void* d_out, int out_size, void* d_ws, size_t ws_size,
                              hipStream_t stream)
{
    (void)in_sizes; (void)n_in; (void)out_size; (void)ws_size;
    const float* x       = (const float*)d_in[0];
    const float* x_      = (const float*)d_in[1];
    const float* pre1_w  = (const float*)d_in[2];
    const float* pre1_a  = (const float*)d_in[4];
    const float* pre2_w  = (const float*)d_in[5];
    const float* pre2_a  = (const float*)d_in[7];
    const float* prek_w1 = (const float*)d_in[8];
    const float* prek_a  = (const float*)d_in[10];
    const float* prek_w2 = (const float*)d_in[11];
    const float* prek_b2 = (const float*)d_in[12];
    float* out = (float*)d_out;

    float* A   = (float*)d_ws;          // (4,48,64,64) = 786432
    float* B   = A + 786432;            // (4,48,64,64)
    float* R0  = B + 786432;            // partial conv half0 (<= 786432)
    float* R1  = R0 + 786432;           // partial conv half1
    float* C   = R1 + 786432;           // (4,48,32,32) = 196608
    float* D   = C + 196608;            // (4,48,32,32)
    float* SK0 = D + 196608;            // (4,9,32,32) = 36864
    float* SK1 = SK0 + 36864;

    const int W1 = 48 * 48 * 9;

    downsample4<<<3072, 256, 0, stream>>>(x_, A);

    // ---- 3 basic blocks @64x64: split-K conv, XCD-owned input slices ----
    conv_tile<64, 64, 4, 3, 2, 2, 24, 48><<<dim3(8, 16, 16), 128, 0, stream>>>(A, pre1_w, R0);
    norm_block<4096, 0, 0><<<dim3(48, 4), 1024, 0, stream>>>(R0, R1, A, pre1_a, B);
    conv_tile<64, 64, 4, 3, 2, 2, 24, 48><<<dim3(8, 16, 16), 128, 0, stream>>>(B, pre1_w + W1, R0);
    norm_block<4096, 0, 0><<<dim3(48, 4), 1024, 0, stream>>>(R0, R1, B, pre1_a + 1, A);
    conv_tile<64, 64, 4, 3, 2, 2, 24, 48><<<dim3(8, 16, 16), 128, 0, stream>>>(A, pre1_w + 2 * W1, R0);
    // third norm fuses maxpool2 -> writes pooled 32x32 planes into C
    norm_block<4096, 0, 1><<<dim3(48, 4), 1024, 0, stream>>>(R0, R1, A, pre1_a + 2, C);

    // ---- 3 basic blocks @32x32: split-K conv ----
    conv_tile<32, 32, 4, 2, 4, 1, 24, 48><<<dim3(8, 8, 24), 128, 0, stream>>>(C, pre2_w, R0);
    norm_block<1024, 0, 0><<<dim3(48, 4), 1024, 0, stream>>>(R0, R0 + 196608, C, pre2_a, D);
    conv_tile<32, 32, 4, 2, 4, 1, 24, 48><<<dim3(8, 8, 24), 128, 0, stream>>>(D, pre2_w + W1, R0);
    norm_block<1024, 0, 0><<<dim3(48, 4), 1024, 0, stream>>>(R0, R0 + 196608, D, pre2_a + 1, C);
    conv_tile<32, 32, 4, 2, 4, 1, 24, 48><<<dim3(8, 8, 24), 128, 0, stream>>>(C, pre2_w + 2 * W1, R0);
    norm_block<1024, 0, 0><<<dim3(48, 4), 1024, 0, stream>>>(R0, R0 + 196608, C, pre2_a + 2, D);

    // ---- kernel-prediction heads ----
    conv_tile<32, 32, 4, 2, 4, 1, 24, 48><<<dim3(8, 8, 24), 128, 0, stream>>>(D, prek_w1, R0);
    norm_block<1024, 1, 0><<<dim3(48, 4), 1024, 0, stream>>>(R0, R0 + 196608, nullptr, prek_a, C);
    conv_tile<32, 32, 4, 3, 4, 1, 24, 9><<<dim3(8, 8, 3), 128, 0, stream>>>(C, prek_w2, SK0);

    apply_fused<<<dim3(16, 64), 256, 0, stream>>>(x, SK0, SK1, prek_b2, out);
}

// Round 10
// 299.860 us; speedup vs baseline: 1.0135x; 1.0135x over previous
//
#include <hip/hip_runtime.h>
#include <cmath>

#define HIDC 48

// ---------------------------------------------------------------------------
// Flattened block mean/var (r10): wave shfl-reduce -> NW partials to LDS ->
// ONE barrier -> every thread sums NW partials itself (broadcast reads).
// No serial thread-0 chain, no trailing barrier. The two reduction passes
// use disjoint LDS regions (pass arg) so no inter-pass barrier is needed.
// red must hold 4*NW floats.
// ---------------------------------------------------------------------------
template <int NW>
__device__ __forceinline__ void block_mv2(float s, float s2, float* red, int pass,
                                          float cntinv, float& m, float& v)
{
#pragma unroll
    for (int off = 32; off > 0; off >>= 1) {
        s  += __shfl_down(s, off);
        s2 += __shfl_down(s2, off);
    }
    const int wid  = threadIdx.x >> 6;
    const int lane = threadIdx.x & 63;
    float* rb = red + pass * 2 * NW;
    if (lane == 0) { rb[wid] = s; rb[NW + wid] = s2; }
    __syncthreads();
    float ts = 0.f, ts2 = 0.f;
#pragma unroll
    for (int i = 0; i < NW; ++i) { ts += rb[i]; ts2 += rb[NW + i]; }
    m = ts * cntinv;
    v = ts2 * cntinv - m * m;
}

// ---------------------------------------------------------------------------
// Split-K partial conv3x3(SAME, zero-pad), NO bias (bias cancels in the
// following instance-norm; SK-conv bias is added in apply_fused).
// Each block: COG couts x ROWS rows x W cols over NCH=24 input channels;
// partial written to out + half*4*COUT*NPIX; the next norm sums partials.
// Grid (z, rt, cg), z=(n,half) fastest => bid%8==z => each XCD owns one
// input slice (r9; neutral-at-worst, keeps L2 locality by construction).
//  - SCALAR staging (r7 lesson: float4 staging tuples demoted to scratch
//    -> 143MB write-back, 57us. Keep scalars.)
//  - Stage addresses precomputed ONCE into off[] (-1 = zero pad).
//  - PW = W+4: conflict-free float2/scalar LDS windows.
//  - Double-buffered LDS, ONE barrier per stage.
//  - r3 lesson: never stage strided-by-4 global reads.
//  - r5 lesson: no grid-wide syncs (54us each).
//  - r4->r6: waves/CU 8->16 was the big conv win; don't trade it away.
// ---------------------------------------------------------------------------
template <int H, int W, int ROWS, int COG, int CPS, int PXT, int NCH, int COUT>
__global__ __launch_bounds__(ROWS*(W/PXT)) void conv_tile(
    const float* __restrict__ in,    // (N, 48, H, W)
    const float* __restrict__ wgt,   // (COUT, 48, 3, 3)
    float* __restrict__ out)         // (2, N, COUT, H, W) partials
{
    constexpr int THREADS = ROWS * (W / PXT);
    constexpr int NPIX = H * W;
    constexpr int PW   = W + 4;
    constexpr int CHSZ = (ROWS + 2) * PW;
    constexpr int LSZ  = CPS * CHSZ;
    constexpr int TXN  = W / PXT;          // threads per row
    constexpr int NS   = NCH / CPS;
    constexpr int LPT  = (LSZ + THREADS - 1) / THREADS;

    __shared__ float plane[2][LSZ];

    const int t    = threadIdx.x;
    const int z    = blockIdx.x;           // (n,half) — fastest => one per XCD
    const int rt   = blockIdx.y;
    const int cg   = blockIdx.z;
    const int half = z & 1;
    const int n    = z >> 1;
    const int co0  = cg * COG;
    const int cin0 = half * NCH;
    const int tx   = t % TXN;
    const int ty   = t / TXN;              // row within tile
    const int x0   = tx * PXT;
    const int r0   = rt * ROWS;
    const size_t OSTRIDE = (size_t)4 * COUT * NPIX;

    float acc[COG][PXT];
#pragma unroll
    for (int co = 0; co < COG; ++co)
#pragma unroll
        for (int p = 0; p < PXT; ++p) acc[co][p] = 0.f;

    const float* inb = in + ((size_t)n * 48 + cin0) * NPIX;

    // precompute staging offsets (loop-invariant across stages)
    int off[LPT];
#pragma unroll
    for (int k = 0; k < LPT; ++k) {
        int i = t + k * THREADS;
        off[k] = -1;
        if (i < LSZ) {
            int ch  = i / CHSZ;
            int rem = i % CHSZ;
            int ly  = rem / PW, lx = rem % PW;
            int gy  = r0 + ly - 1, gx = lx - 1;
            if (gy >= 0 && gy < H && gx >= 0 && gx < W)
                off[k] = ch * NPIX + gy * W + gx;
        }
    }

    // prefetch stage 0
    float pref[LPT];
#pragma unroll
    for (int k = 0; k < LPT; ++k)
        pref[k] = (off[k] >= 0) ? inb[off[k]] : 0.f;

    int buf = 0;
    for (int s = 0; s < NS; ++s) {
        float cur[LPT];
#pragma unroll
        for (int k = 0; k < LPT; ++k) cur[k] = pref[k];
        if (s + 1 < NS) {
            const float* nb = inb + (size_t)(s + 1) * CPS * NPIX;
#pragma unroll
            for (int k = 0; k < LPT; ++k)
                pref[k] = (off[k] >= 0) ? nb[off[k]] : 0.f;
        }
#pragma unroll
        for (int k = 0; k < LPT; ++k) {
            int i = t + k * THREADS;
            if (i < LSZ) plane[buf][i] = cur[k];
        }
        __syncthreads();

#pragma unroll
        for (int c = 0; c < CPS; ++c) {
            const float* P = &plane[buf][c * CHSZ];
            float wv[COG][9];
#pragma unroll
            for (int co = 0; co < COG; ++co)
#pragma unroll
                for (int k = 0; k < 9; ++k)
                    wv[co][k] = wgt[((size_t)(co0 + co) * 48 + cin0 + s * CPS + c) * 9 + k];
            // window rows ty..ty+2, cols x0..x0+PXT+1
            float vr[3][PXT + 2];
            if constexpr (PXT == 2) {
#pragma unroll
                for (int r = 0; r < 3; ++r) {
                    float2 a = *(const float2*)(P + (ty + r) * PW + x0);
                    float2 b = *(const float2*)(P + (ty + r) * PW + x0 + 2);
                    vr[r][0] = a.x; vr[r][1] = a.y; vr[r][2] = b.x; vr[r][3] = b.y;
                }
            } else {
#pragma unroll
                for (int r = 0; r < 3; ++r)
#pragma unroll
                    for (int j = 0; j < PXT + 2; ++j)
                        vr[r][j] = P[(ty + r) * PW + x0 + j];
            }
#pragma unroll
            for (int co = 0; co < COG; ++co)
#pragma unroll
                for (int p = 0; p < PXT; ++p) {
                    float s0 = vr[0][p]     * wv[co][0] + vr[0][p + 1] * wv[co][1]
                             + vr[0][p + 2] * wv[co][2] + vr[1][p]     * wv[co][3]
                             + vr[1][p + 1] * wv[co][4] + vr[1][p + 2] * wv[co][5]
                             + vr[2][p]     * wv[co][6] + vr[2][p + 1] * wv[co][7]
                             + vr[2][p + 2] * wv[co][8];
                    acc[co][p] += s0;
                }
        }
        buf ^= 1;
    }

#pragma unroll
    for (int co = 0; co < COG; ++co) {
        float* op = out + half * OSTRIDE
                  + (((size_t)n * COUT + co0 + co) * H + r0 + ty) * W + x0;
        if (PXT == 2) {
            *(float2*)op = make_float2(acc[co][0], acc[co][1]);
        } else {
#pragma unroll
            for (int p = 0; p < PXT; ++p) op[p] = acc[co][p];
        }
    }
}

// ---------------------------------------------------------------------------
// Per-plane epilogue on the SUM of two split-K partials:
//   MODE 0: inorm, prelu, inorm, +res    MODE 1: inorm, prelu
//   POOL 1: (MODE 0, NPIX=4096) threads own 2x2 quads; after the residual
//           add, pools max-2x2 in-register and writes the 32x32 plane.
// r10: THREADS template param (512 @64², 256 @32² — cheaper barriers than
// 1024) + flattened single-barrier reductions (block_mv2). Non-POOL path
// is float4-vectorized (thread owns TY consecutive elements).
// ---------------------------------------------------------------------------
template <int NPIX, int MODE, int POOL, int THREADS>
__global__ __launch_bounds__(THREADS) void norm_block(
    const float* __restrict__ c0,
    const float* __restrict__ c1,
    const float* __restrict__ res,
    const float* __restrict__ aptr,
    float* __restrict__ out)
{
    constexpr int TY = NPIX / THREADS;
    constexpr int NW = THREADS / 64;
    constexpr int QT = POOL ? (NPIX / 4 / THREADS) : 0;   // quads per thread
    __shared__ float red[4 * NW];
    const int t  = threadIdx.x;
    const int co = blockIdx.x;
    const int n  = blockIdx.y;
    const size_t base = ((size_t)n * 48 + co) * NPIX;
    constexpr float cntinv = 1.f / (float)NPIX;

    float acc[TY];
    if constexpr (POOL) {
        // quad qid = t + k*THREADS: rows (2i,2i+1), cols (2j,2j+1)
#pragma unroll
        for (int k = 0; k < QT; ++k) {
            int qid = t + k * THREADS;
            int i = qid >> 5, j = qid & 31;
            size_t q = base + (size_t)i * 128 + j * 2;
            float2 a0 = *(const float2*)(c0 + q);
            float2 a1 = *(const float2*)(c0 + q + 64);
            float2 b0 = *(const float2*)(c1 + q);
            float2 b1 = *(const float2*)(c1 + q + 64);
            acc[4 * k + 0] = a0.x + b0.x; acc[4 * k + 1] = a0.y + b0.y;
            acc[4 * k + 2] = a1.x + b1.x; acc[4 * k + 3] = a1.y + b1.y;
        }
    } else {
        const size_t q = base + (size_t)t * TY;
#pragma unroll
        for (int r = 0; r < TY / 4; ++r) {
            float4 a4 = *(const float4*)(c0 + q + r * 4);
            float4 b4 = *(const float4*)(c1 + q + r * 4);
            acc[4 * r + 0] = a4.x + b4.x; acc[4 * r + 1] = a4.y + b4.y;
            acc[4 * r + 2] = a4.z + b4.z; acc[4 * r + 3] = a4.w + b4.w;
        }
    }

    {
        float s = 0.f, s2 = 0.f;
#pragma unroll
        for (int r = 0; r < TY; ++r) { s += acc[r]; s2 += acc[r] * acc[r]; }
        float m, v;
        block_mv2<NW>(s, s2, red, 0, cntinv, m, v);
        float rr = rsqrtf(v + 1e-5f);
#pragma unroll
        for (int r = 0; r < TY; ++r) acc[r] = (acc[r] - m) * rr;
    }

    const float a = aptr[0];
#pragma unroll
    for (int r = 0; r < TY; ++r) acc[r] = acc[r] >= 0.f ? acc[r] : a * acc[r];

    if (MODE == 0) {
        float s = 0.f, s2 = 0.f;
#pragma unroll
        for (int r = 0; r < TY; ++r) { s += acc[r]; s2 += acc[r] * acc[r]; }
        float m, v;
        block_mv2<NW>(s, s2, red, 1, cntinv, m, v);
        float rr = rsqrtf(v + 1e-5f);
        if constexpr (POOL) {
#pragma unroll
            for (int k = 0; k < QT; ++k) {
                int qid = t + k * THREADS;
                int i = qid >> 5, j = qid & 31;
                size_t q = base + (size_t)i * 128 + j * 2;
                float2 r0v = *(const float2*)(res + q);
                float2 r1v = *(const float2*)(res + q + 64);
                acc[4 * k + 0] = (acc[4 * k + 0] - m) * rr + r0v.x;
                acc[4 * k + 1] = (acc[4 * k + 1] - m) * rr + r0v.y;
                acc[4 * k + 2] = (acc[4 * k + 2] - m) * rr + r1v.x;
                acc[4 * k + 3] = (acc[4 * k + 3] - m) * rr + r1v.y;
            }
        } else {
            const size_t q = base + (size_t)t * TY;
#pragma unroll
            for (int r = 0; r < TY / 4; ++r) {
                float4 r4 = *(const float4*)(res + q + r * 4);
                acc[4 * r + 0] = (acc[4 * r + 0] - m) * rr + r4.x;
                acc[4 * r + 1] = (acc[4 * r + 1] - m) * rr + r4.y;
                acc[4 * r + 2] = (acc[4 * r + 2] - m) * rr + r4.z;
                acc[4 * r + 3] = (acc[4 * r + 3] - m) * rr + r4.w;
            }
        }
    }

    if constexpr (POOL) {
        const size_t ob = ((size_t)n * 48 + co) << 10;
#pragma unroll
        for (int k = 0; k < QT; ++k) {
            int qid = t + k * THREADS;
            out[ob + qid] = fmaxf(fmaxf(acc[4 * k + 0], acc[4 * k + 1]),
                                  fmaxf(acc[4 * k + 2], acc[4 * k + 3]));
        }
    } else {
        const size_t q = base + (size_t)t * TY;
#pragma unroll
        for (int r = 0; r < TY / 4; ++r)
            *(float4*)(out + q + r * 4) = make_float4(acc[4 * r], acc[4 * r + 1],
                                                      acc[4 * r + 2], acc[4 * r + 3]);
    }
}

// ---------------------------------------------------------------------------
__global__ __launch_bounds__(256) void downsample4(const float* __restrict__ xin,
                                                   float* __restrict__ o)
{
    int idx = blockIdx.x * 256 + threadIdx.x;        // 786432
    int j = idx & 63;
    int i = (idx >> 6) & 63;
    int nc = idx >> 12;
    o[idx] = xin[((size_t)nc * 256 + i * 4) * 256 + j * 4];
}

// ---------------------------------------------------------------------------
// Fused: bilinear 8x upsample of skernel partials (sk0+sk1+bias), per-pixel
// softmax, 3x3 reflect-padded apply to x.
// r10: TWO output rows per block — grid (16,128). The r8(1-row)/r9(4-row)
// null pair isolated the trade: reuse vs LDS-capped occupancy. 2-row is the
// sweet spot: 2x x-reuse at kvs[2][9][256]+skr = ~21.5KB -> ~7 blocks/CU
// (~28 waves) vs r9's ~3. All 12 x-row loads hoisted; halo via shuffle.
// ---------------------------------------------------------------------------
__global__ __launch_bounds__(256) void apply_fused(const float* __restrict__ x,
                                                   const float* __restrict__ sk0,
                                                   const float* __restrict__ sk1,
                                                   const float* __restrict__ kb2,
                                                   float* __restrict__ out)
{
    __shared__ float skr[9][3][32];
    __shared__ float kvs[2][9][256];
    const int bx = blockIdx.x;
    const int n  = bx >> 2;
    const int cg = bx & 3;
    const int h0 = blockIdx.y * 2;
    const int t  = threadIdx.x;

    const int wq = t & 63;           // lane within wave == pixel quad
    const int cl = t >> 6;           // wave id == channel subgroup
    const int w4 = wq * 4;
    const int c0ch = cg * 12 + cl * 3;
    const float* xb = x + ((size_t)n * HIDC + c0ch) * 65536;
    float* ob = out + ((size_t)n * HIDC + c0ch) * 65536;

    // hoist all 12 x-row loads (rows h0-1 .. h0+2, reflect-mapped)
    float4 F[3][4];
#pragma unroll
    for (int c = 0; c < 3; ++c) {
        const float* xp = xb + (size_t)c * 65536;
#pragma unroll
        for (int k = 0; k < 4; ++k) {
            int g = h0 - 1 + k;
            g = (g < 0) ? 1 : (g > 255 ? 254 : g);
            F[c][k] = *(const float4*)(xp + g * 256 + w4);
        }
    }

    // stage the 3 skernel source rows this block can touch: r_0 .. r_0+2
    const int r_0 = (h0 * 31) / 255;
    for (int i = t; i < 864; i += 256) {
        int p = i / 96, rem = i % 96;
        int rsel = rem >> 5, c = rem & 31;
        int rr = min(r_0 + rsel, 31);
        int idx = ((n * 9 + p) * 32 + rr) * 32 + c;
        skr[p][rsel][c] = sk0[idx] + sk1[idx] + kb2[p];
    }
    __syncthreads();

    // per-pixel bilinear + softmax for 2 rows (thread t = column t)
    {
        float fcs = (float)t * 31.0f / 255.0f;
        int c0 = (int)fcs;
        float fx = fcs - (float)c0;
        int c1 = min(c0 + 1, 31);
#pragma unroll
        for (int ro = 0; ro < 2; ++ro) {
            float fs = (float)(h0 + ro) * 31.0f / 255.0f;
            int rh = (int)fs;
            float fh = fs - (float)rh;
            int a_ = rh - r_0;           // 0 or 1
            int b_ = a_ + 1;             // 1 or 2
            float kv[9];
            float mx = -1e30f;
#pragma unroll
            for (int p = 0; p < 9; ++p) {
                float v0 = skr[p][a_][c0] * (1.f - fx) + skr[p][a_][c1] * fx;
                float v1 = skr[p][b_][c0] * (1.f - fx) + skr[p][b_][c1] * fx;
                float v  = v0 * (1.f - fh) + v1 * fh;
                kv[p] = v;
                mx = fmaxf(mx, v);
            }
            float ss = 0.f;
#pragma unroll
            for (int p = 0; p < 9; ++p) { kv[p] = __expf(kv[p] - mx); ss += kv[p]; }
            float inv = 1.f / ss;
#pragma unroll
            for (int p = 0; p < 9; ++p) kvs[ro][p][t] = kv[p] * inv;
        }
    }
    __syncthreads();

#pragma unroll
    for (int ro = 0; ro < 2; ++ro) {
        float kv[4][9];
#pragma unroll
        for (int p = 0; p < 9; ++p) {
            float4 v = *(const float4*)&kvs[ro][p][w4];
            kv[0][p] = v.x; kv[1][p] = v.y; kv[2][p] = v.z; kv[3][p] = v.w;
        }
#pragma unroll
        for (int c = 0; c < 3; ++c) {
            float4 fm = F[c][ro];
            float4 fc = F[c][ro + 1];
            float4 fp = F[c][ro + 2];
            float lm = __shfl_up(fm.w, 1);   if (wq == 0)  lm = fm.y;
            float lc = __shfl_up(fc.w, 1);   if (wq == 0)  lc = fc.y;
            float lp = __shfl_up(fp.w, 1);   if (wq == 0)  lp = fp.y;
            float rmr = __shfl_down(fm.x, 1); if (wq == 63) rmr = fm.z;
            float rcr = __shfl_down(fc.x, 1); if (wq == 63) rcr = fc.z;
            float rpr = __shfl_down(fp.x, 1); if (wq == 63) rpr = fp.z;
            float vm[6] = { lm, fm.x, fm.y, fm.z, fm.w, rmr };
            float vc[6] = { lc, fc.x, fc.y, fc.z, fc.w, rcr };
            float vp[6] = { lp, fp.x, fp.y, fp.z, fp.w, rpr };
            float4 o;
            float* op = &o.x;
#pragma unroll
            for (int j = 0; j < 4; ++j) {
                op[j] = kv[j][0] * vm[j] + kv[j][1] * vm[j + 1] + kv[j][2] * vm[j + 2]
                      + kv[j][3] * vc[j] + kv[j][4] * vc[j + 1] + kv[j][5] * vc[j + 2]
                      + kv[j][6] * vp[j] + kv[j][7] * vp[j + 1] + kv[j][8] * vp[j + 2];
            }
            *(float4*)(ob + (size_t)c * 65536 + (h0 + ro) * 256 + w4) = o;
        }
    }
}

extern "C" void kernel_launch(void* const* d_in, const int* in_sizes, int n_in,
                              void* d_out, int out_size, void* d_ws, size_t ws_size,
                              hipStream_t stream)
{
    (void)in_sizes; (void)n_in; (void)out_size; (void)ws_size;
    const float* x       = (const float*)d_in[0];
    const float* x_      = (const float*)d_in[1];
    const float* pre1_w  = (const float*)d_in[2];
    const float* pre1_a  = (const float*)d_in[4];
    const float* pre2_w  = (const float*)d_in[5];
    const float* pre2_a  = (const float*)d_in[7];
    const float* prek_w1 = (const float*)d_in[8];
    const float* prek_a  = (const float*)d_in[10];
    const float* prek_w2 = (const float*)d_in[11];
    const float* prek_b2 = (const float*)d_in[12];
    float* out = (float*)d_out;

    float* A   = (float*)d_ws;          // (4,48,64,64) = 786432
    float* B   = A + 786432;            // (4,48,64,64)
    float* R0  = B + 786432;            // partial conv half0 (<= 786432)
    float* R1  = R0 + 786432;           // partial conv half1
    float* C   = R1 + 786432;           // (4,48,32,32) = 196608
    float* D   = C + 196608;            // (4,48,32,32)
    float* SK0 = D + 196608;            // (4,9,32,32) = 36864
    float* SK1 = SK0 + 36864;

    const int W1 = 48 * 48 * 9;

    downsample4<<<3072, 256, 0, stream>>>(x_, A);

    // ---- 3 basic blocks @64x64: split-K conv, XCD-owned input slices ----
    conv_tile<64, 64, 4, 3, 2, 2, 24, 48><<<dim3(8, 16, 16), 128, 0, stream>>>(A, pre1_w, R0);
    norm_block<4096, 0, 0, 512><<<dim3(48, 4), 512, 0, stream>>>(R0, R1, A, pre1_a, B);
    conv_tile<64, 64, 4, 3, 2, 2, 24, 48><<<dim3(8, 16, 16), 128, 0, stream>>>(B, pre1_w + W1, R0);
    norm_block<4096, 0, 0, 512><<<dim3(48, 4), 512, 0, stream>>>(R0, R1, B, pre1_a + 1, A);
    conv_tile<64, 64, 4, 3, 2, 2, 24, 48><<<dim3(8, 16, 16), 128, 0, stream>>>(A, pre1_w + 2 * W1, R0);
    // third norm fuses maxpool2 -> writes pooled 32x32 planes into C
    norm_block<4096, 0, 1, 512><<<dim3(48, 4), 512, 0, stream>>>(R0, R1, A, pre1_a + 2, C);

    // ---- 3 basic blocks @32x32: split-K conv ----
    conv_tile<32, 32, 4, 2, 4, 1, 24, 48><<<dim3(8, 8, 24), 128, 0, stream>>>(C, pre2_w, R0);
    norm_block<1024, 0, 0, 256><<<dim3(48, 4), 256, 0, stream>>>(R0, R0 + 196608, C, pre2_a, D);
    conv_tile<32, 32, 4, 2, 4, 1, 24, 48><<<dim3(8, 8, 24), 128, 0, stream>>>(D, pre2_w + W1, R0);
    norm_block<1024, 0, 0, 256><<<dim3(48, 4), 256, 0, stream>>>(R0, R0 + 196608, D, pre2_a + 1, C);
    conv_tile<32, 32, 4, 2, 4, 1, 24, 48><<<dim3(8, 8, 24), 128, 0, stream>>>(C, pre2_w + 2 * W1, R0);
    norm_block<1024, 0, 0, 256><<<dim3(48, 4), 256, 0, stream>>>(R0, R0 + 196608, C, pre2_a + 2, D);

    // ---- kernel-prediction heads ----
    conv_tile<32, 32, 4, 2, 4, 1, 24, 48><<<dim3(8, 8, 24), 128, 0, stream>>>(D, prek_w1, R0);
    norm_block<1024, 1, 0, 256><<<dim3(48, 4), 256, 0, stream>>>(R0, R0 + 196608, nullptr, prek_a, C);
    conv_tile<32, 32, 4, 3, 4, 1, 24, 9><<<dim3(8, 8, 3), 128, 0, stream>>>(C, prek_w2, SK0);

    apply_fused<<<dim3(16, 128), 256, 0, stream>>>(x, SK0, SK1, prek_b2, out);
}